// Round 17
// baseline (26.111 us; speedup 1.0000x reference)
//
#include <hip/hip_runtime.h>
#include <hip/hip_bf16.h>

#define N_X    65536
#define N_IND  1024
#define N_DESC 64
#define L2E    1.4426950408889634f
#define L2E2   2.8853900817779268f
#define SKIP_THR (-60.0f)         // 2^-60 * 1024 * |alpha| ~ 4e-15 << tol

typedef __attribute__((ext_vector_type(8)))  short short8;
typedef __attribute__((ext_vector_type(16))) float f32x16;

static __device__ __forceinline__ ushort f2bf(float f) {
    union { float f; unsigned u; } a; a.f = f;
    unsigned r = a.u + 0x7FFF + ((a.u >> 16) & 1);   // RNE to bf16
    return (ushort)(r >> 16);
}
static __device__ __forceinline__ float bf2f(ushort h) {
    union { unsigned u; float f; } a; a.u = (unsigned)h << 16;
    return a.f;
}

// ---------------------------------------------------------------------------
// Round 17: 32x32x16 MFMA + FRAGMENT-LINEAR z-panel.
// R13-R15 proved the loop is LDS-issue-bound; R16 proved trading LDS for
// VALU/prologue loses. This round moves more bytes per LDS instruction:
// one 32x32x64 tile = 4 ds_read_b128 (vs 8 for the same volume at 16x16),
// and the panel is stored in MFMA-consumption order so every A-read is
// base + lane*16 (wave-linear 1 KB, conflict-free, no swizzle).
//   element (row,k) @ (row>>5)*4096 + (k>>4)*1024
//                     + (((k>>3)&1)*32 + (row&31))*16 + (k&7)*2
// Waves: 8 strips of 32 x-cols x 2 z-panel-halves. B-frags (x) in VGPRs.
// Skip test per tile (R15-style z2m bound, amortized over 4x volume):
//   skip iff L2E2*max16(D) - z2m[t] < SKIP_THR + xs2   (per-lane xs2)
// Kept path (never taken here) reads z2/al from LDS exactly as R12 math.
// C/D (verified m74/m101): col=lane&31, row=(reg&3)+8*(reg>>2)+4*(lane>>5).
// A/B: row|col=lane&31, k=(lane>>5)*8+e (same verified family as 16x16x32).
// ---------------------------------------------------------------------------
__global__ __launch_bounds__(1024) void igpr_fused(
        const float* __restrict__ x, const float* __restrict__ z,
        const float* __restrict__ alpha, const float* __restrict__ ls,
        float* __restrict__ out) {
    struct SM {
        uint4 zt[N_IND * 8];      // 128 KB, fragment-linear
        float z2[N_IND];          // log2e * ||zw||^2 (bf16-consistent)
        float al[N_IND];          // alpha
        float z2m[32];            // per-32-tile min z2
        float colPart[16][32];    // per-wave kept-path partials
    };
    __shared__ SM sm;             // ~138.1 KB

    const int tid  = threadIdx.x;
    const int lane = tid & 63;
    const int wave = tid >> 6;                 // 0..15
    const int col5 = lane & 31;                // x-col in strip / D col
    const int half = lane >> 5;                // k-half
    const int strip = wave & 7;
    const int zhalf = wave >> 3;               // which 16 z-tiles
    const int jb = blockIdx.x * 256;
    const int j  = jb + strip * 32 + col5;     // this lane's x column

    // ---- x loads issued first (in flight under z staging) ----
    const float* xr = x + (size_t)j * N_DESC;
    float4 xv[8];
#pragma unroll
    for (int c = 0; c < 4; ++c) {
        xv[2 * c]     = *reinterpret_cast<const float4*>(xr + 16 * c + 8 * half);
        xv[2 * c + 1] = *reinterpret_cast<const float4*>(xr + 16 * c + 8 * half + 4);
    }
    const float alv = alpha[tid];

    // ---- z staging: thread owns granule-col gq for 8 rows (rr + 128*rb) ----
    // consecutive lanes -> consecutive rows -> contiguous 512B LDS runs
    const int gq = tid >> 7;          // 0..7 (fixed k-granule)
    const int rr = tid & 127;
    float wz[8];
#pragma unroll
    for (int e = 0; e < 8; ++e) wz[e] = __expf(-0.5f * ls[gq * 8 + e]);

    char* zbw = reinterpret_cast<char*>(sm.zt);
#define ZLD(rb, A, B)                                                          \
    {                                                                          \
        const float* zp_ = z + (size_t)((rb) * 128 + rr) * 64 + gq * 8;        \
        A = *reinterpret_cast<const float4*>(zp_);                             \
        B = *reinterpret_cast<const float4*>(zp_ + 4);                         \
    }
#define ZCVT(rb, A, B)                                                         \
    {                                                                          \
        float vv_[8] = {A.x, A.y, A.z, A.w, B.x, B.y, B.z, B.w};               \
        ushort hb_[8];                                                         \
        _Pragma("unroll")                                                      \
        for (int e = 0; e < 8; ++e) hb_[e] = f2bf(vv_[e] * wz[e]);             \
        uint4 u_ = make_uint4(                                                 \
            (unsigned)hb_[0] | ((unsigned)hb_[1] << 16),                       \
            (unsigned)hb_[2] | ((unsigned)hb_[3] << 16),                       \
            (unsigned)hb_[4] | ((unsigned)hb_[5] << 16),                       \
            (unsigned)hb_[6] | ((unsigned)hb_[7] << 16));                      \
        int row_ = (rb) * 128 + rr;                                            \
        int ad_  = (row_ >> 5) * 4096 + (gq >> 1) * 1024                       \
                 + ((gq & 1) * 32 + (row_ & 31)) * 16;                         \
        *reinterpret_cast<uint4*>(zbw + ad_) = u_;                             \
    }
    {
        float4 cA, cB, nA, nB;
        ZLD(0, cA, cB)
        ZLD(1, nA, nB)
        ZCVT(0, cA, cB)  ZLD(2, cA, cB)
        ZCVT(1, nA, nB)  ZLD(3, nA, nB)
        ZCVT(2, cA, cB)  ZLD(4, cA, cB)
        ZCVT(3, nA, nB)  ZLD(5, nA, nB)
        ZCVT(4, cA, cB)  ZLD(6, cA, cB)
        ZCVT(5, nA, nB)  ZLD(7, nA, nB)
        ZCVT(6, cA, cB)
        ZCVT(7, nA, nB)
    }
#undef ZLD
#undef ZCVT
    sm.al[tid] = alv;

    __syncthreads();   // panel complete

    // ---- z2 pass: thread = row, re-read own row (bf16-consistent norms) ----
    {
        const char* zb = reinterpret_cast<const char*>(sm.zt);
        const int tbase = (tid >> 5) * 4096;
        float sq = 0.f;
#pragma unroll
        for (int gr = 0; gr < 8; ++gr) {
            int ad = tbase + (gr >> 1) * 1024 + ((gr & 1) * 32 + (tid & 31)) * 16;
            uint4 u = *reinterpret_cast<const uint4*>(zb + ad);
            unsigned ws[4] = {u.x, u.y, u.z, u.w};
#pragma unroll
            for (int w = 0; w < 4; ++w) {
                union { unsigned u; float f; } lo, hi;
                lo.u = ws[w] << 16;
                hi.u = ws[w] & 0xFFFF0000u;
                sq = fmaf(lo.f, lo.f, sq);
                sq = fmaf(hi.f, hi.f, sq);
            }
        }
        sm.z2[tid] = sq * L2E;
    }

    __syncthreads();   // z2 complete

    if (tid < 32) {    // per-32-tile min bound
        float mn = sm.z2[tid * 32];
#pragma unroll
        for (int i = 1; i < 32; ++i) mn = fminf(mn, sm.z2[tid * 32 + i]);
        sm.z2m[tid] = mn;
    }
    if (tid < 512) sm.colPart[tid >> 5][tid & 31] = 0.f;

    // ---- x conversion (overlaps z2m): B-frags + xs2 ----
    short8 B0, B1, B2, B3;
    float xs2;
    {
        float sq = 0.f;
        short8 bb[4];
#pragma unroll
        for (int c = 0; c < 4; ++c) {
            float w8[8];
#pragma unroll
            for (int e = 0; e < 8; ++e)
                w8[e] = __expf(-0.5f * ls[16 * c + 8 * half + e]);
            float vv[8] = {xv[2 * c].x, xv[2 * c].y, xv[2 * c].z, xv[2 * c].w,
                           xv[2 * c + 1].x, xv[2 * c + 1].y,
                           xv[2 * c + 1].z, xv[2 * c + 1].w};
#pragma unroll
            for (int e = 0; e < 8; ++e) {
                ushort h = f2bf(vv[e] * w8[e]);
                bb[c][e] = (short)h;
                float xf = bf2f(h);
                sq = fmaf(xf, xf, sq);
            }
        }
        B0 = bb[0]; B1 = bb[1]; B2 = bb[2]; B3 = bb[3];
        sq += __shfl_xor(sq, 32);   // other k-half
        xs2 = sq * L2E;
    }

    __syncthreads();   // z2m + colPart ready (LDS read-only from here)

    const char* zb = reinterpret_cast<const char*>(sm.zt);
    float acc = 0.f;
    const float thr = SKIP_THR + xs2;   // skip iff L2E2*maxd - z2m < thr

#pragma unroll 2
    for (int tt = 0; tt < 16; ++tt) {
        const int t = zhalf * 16 + tt;
        const char* tb = zb + t * 4096 + lane * 16;
        short8 a0 = *reinterpret_cast<const short8*>(tb);
        short8 a1 = *reinterpret_cast<const short8*>(tb + 1024);
        short8 a2 = *reinterpret_cast<const short8*>(tb + 2048);
        short8 a3 = *reinterpret_cast<const short8*>(tb + 3072);
        float zm = sm.z2m[t];

        f32x16 D = {0.f, 0.f, 0.f, 0.f, 0.f, 0.f, 0.f, 0.f,
                    0.f, 0.f, 0.f, 0.f, 0.f, 0.f, 0.f, 0.f};
        D = __builtin_amdgcn_mfma_f32_32x32x16_bf16(a0, B0, D, 0, 0, 0);
        D = __builtin_amdgcn_mfma_f32_32x32x16_bf16(a1, B1, D, 0, 0, 0);
        D = __builtin_amdgcn_mfma_f32_32x32x16_bf16(a2, B2, D, 0, 0, 0);
        D = __builtin_amdgcn_mfma_f32_32x32x16_bf16(a3, B3, D, 0, 0, 0);

        float m0 = fmaxf(fmaxf(D[0], D[1]),  fmaxf(D[2], D[3]));
        float m1 = fmaxf(fmaxf(D[4], D[5]),  fmaxf(D[6], D[7]));
        float m2 = fmaxf(fmaxf(D[8], D[9]),  fmaxf(D[10], D[11]));
        float m3 = fmaxf(fmaxf(D[12], D[13]), fmaxf(D[14], D[15]));
        float maxd  = fmaxf(fmaxf(m0, m1), fmaxf(m2, m3));
        float bound = fmaf(maxd, L2E2, -zm);

        if (!__all(bound < thr)) {
            // rare path: exact per-element contribution (R12 math)
#pragma unroll
            for (int r = 0; r < 16; ++r) {
                int row = t * 32 + (r & 3) + 8 * (r >> 2) + 4 * half;
                float arg = fmaf(D[r], L2E2, -(sm.z2[row] + xs2));
                acc = fmaf(sm.al[row], __builtin_amdgcn_exp2f(arg), acc);
            }
        }
    }

    acc += __shfl_xor(acc, 32);       // combine the two k-half row-sets
    if (lane < 32) sm.colPart[wave][lane] = acc;

    __syncthreads();

    if (tid < 256) {                  // combine the two z-halves, write out
        int cg = tid >> 5, c = tid & 31;
        out[jb + tid] = sm.colPart[cg][c] + sm.colPart[cg + 8][c];
    }
}

extern "C" void kernel_launch(void* const* d_in, const int* in_sizes, int n_in,
                              void* d_out, int out_size, void* d_ws, size_t ws_size,
                              hipStream_t stream) {
    const float* x     = (const float*)d_in[0];   // (65536, 64)
    const float* z     = (const float*)d_in[1];   // (1024, 64)
    const float* alpha = (const float*)d_in[2];   // (1024,)
    const float* ls    = (const float*)d_in[3];   // (64,)
    float* out = (float*)d_out;                   // (65536, 1)

    igpr_fused<<<dim3(N_X / 256), dim3(1024), 0, stream>>>(x, z, alpha, ls, out);
}

// Round 18
// 24.499 us; speedup vs baseline: 1.0658x; 1.0658x over previous
//
#include <hip/hip_runtime.h>
#include <hip/hip_bf16.h>

#define N_X    65536
#define N_IND  1024
#define N_DESC 64
#define NCHUNK 2
#define CROWS  (N_IND / NCHUNK)   // 512 z-rows per chunk
#define TILES  (CROWS / 16)       // 32 MFMA row-tiles per chunk
#define L2E    1.4426950408889634f
#define L2E2   2.8853900817779268f
#define SKIP_THR (-60.0f)         // 2^-60 * 1024 * |alpha| ~ 4e-15 << tol

typedef __attribute__((ext_vector_type(8))) short  short8;
typedef __attribute__((ext_vector_type(4))) float  f32x4;
typedef __attribute__((ext_vector_type(2))) float  f32x2;

static __device__ __forceinline__ ushort f2bf(float f) {
    union { float f; unsigned u; } a; a.f = f;
    unsigned r = a.u + 0x7FFF + ((a.u >> 16) & 1);   // RNE to bf16
    return (ushort)(r >> 16);
}
static __device__ __forceinline__ float bf2f(ushort h) {
    union { unsigned u; float f; } a; a.u = (unsigned)h << 16;
    return a.f;
}

// ---------------------------------------------------------------------------
// zero: out[j] = 0 (atomic accumulation target; 2 commutative adds per col
// -> bit-deterministic).
// ---------------------------------------------------------------------------
__global__ __launch_bounds__(1024) void igpr_zero(float* __restrict__ out) {
    out[blockIdx.x * 1024 + threadIdx.x] = 0.f;
}

// ---------------------------------------------------------------------------
// Round 18 = R15 (best verified structure: swizzled z-panel in LDS, skip
// bound z2m, pipelined staging) re-parameterized to cut chip-wide LDS work:
//   S=2 strips/wave (A b128 reads SHARED by both strips' MFMAs) x half-panel
//   z-chunks (CROWS=512) -> grid (128 cols x 2 chunks) = 256 blocks, full
//   chip. Per-CU loop b128: 2048 -> 1024; staging rows: 1024 -> 512.
// Output via atomicAdd onto zeroed out[] (exactly 2 adds per col, float add
// commutative -> deterministic; no part buffer, no reduce kernel).
// Skip test per tile over both strips: maxd(8 vals); thr = SKIP+min(xs2).
// Kept path (never taken for this data) = exact R12 math per strip.
// Swizzle: byte colb ^= (row&7)<<4 on BOTH write and read (rule #21).
// C/D: col = lane&15 (x-col), row = 4*(lane>>4)+reg (z-row).
// ---------------------------------------------------------------------------
__global__ __launch_bounds__(1024) void igpr_fused(
        const float* __restrict__ x, const float* __restrict__ z,
        const float* __restrict__ alpha, const float* __restrict__ ls,
        float* __restrict__ out) {
    struct SM {
        uint4 zt[CROWS * 8];   // 512 rows * 128 B = 64 KB (swizzled)
        float z2[CROWS];       // log2e * ||zw||^2
        float al[CROWS];       // alpha
        float z2m[TILES];      // per-tile min of z2 (skip bound)
    };
    __shared__ SM sm;          // ~68.1 KB

    const int tid  = threadIdx.x;
    const int lane = tid & 63;
    const int wave = tid >> 6;                    // 0..15
    const int p = lane & 15;                      // x-col within strip / D col
    const int g = lane >> 4;                      // k-group; D rows 4g..4g+3
    const int c  = blockIdx.y;                    // z-chunk
    const int j0 = blockIdx.x * 512 + wave * 32;  // wave's first x column

    // ---- issue x loads immediately (both strips); consumed after staging ----
    const float* xr0 = x + (size_t)(j0 + p) * N_DESC;
    const float* xr1 = x + (size_t)(j0 + 16 + p) * N_DESC;
    float4 xa0 = *reinterpret_cast<const float4*>(xr0 + g * 8);
    float4 xa1 = *reinterpret_cast<const float4*>(xr0 + g * 8 + 4);
    float4 xa2 = *reinterpret_cast<const float4*>(xr0 + 32 + g * 8);
    float4 xa3 = *reinterpret_cast<const float4*>(xr0 + 32 + g * 8 + 4);
    float4 xb0 = *reinterpret_cast<const float4*>(xr1 + g * 8);
    float4 xb1 = *reinterpret_cast<const float4*>(xr1 + g * 8 + 4);
    float4 xb2 = *reinterpret_cast<const float4*>(xr1 + 32 + g * 8);
    float4 xb3 = *reinterpret_cast<const float4*>(xr1 + 32 + g * 8 + 4);

    // ---- per-thread staging weights: cols gr*8 .. gr*8+7 ----
    const int gr = tid & 7;           // granule column-group (fixed per thread)
    const int row_base = tid >> 3;    // row = rb*128 + row_base (0..127)
    float wz[8];
#pragma unroll
    for (int e = 0; e < 8; ++e) wz[e] = __expf(-0.5f * ls[gr * 8 + e]);

    // ---- z staging: 4 granules, 2-deep pipelined, swizzled dest ----
    char* zbw = reinterpret_cast<char*>(sm.zt);
    const float* zc = z + (size_t)c * CROWS * N_DESC;

#define ZLD(rb, A, B)                                                          \
    {                                                                          \
        const float* zp_ = zc + (size_t)((rb) * 128 + row_base) * 64 + gr * 8; \
        A = *reinterpret_cast<const float4*>(zp_);                             \
        B = *reinterpret_cast<const float4*>(zp_ + 4);                         \
    }
#define ZCVT(rb, A, B)                                                         \
    {                                                                          \
        float vv_[8] = {A.x, A.y, A.z, A.w, B.x, B.y, B.z, B.w};               \
        ushort hb_[8]; float sq_ = 0.f;                                        \
        _Pragma("unroll")                                                      \
        for (int e = 0; e < 8; ++e) {                                          \
            ushort h_ = f2bf(vv_[e] * wz[e]);                                  \
            hb_[e] = h_;                                                       \
            float vr_ = bf2f(h_);                                              \
            sq_ = fmaf(vr_, vr_, sq_);                                         \
        }                                                                      \
        uint4 u_ = make_uint4(                                                 \
            (unsigned)hb_[0] | ((unsigned)hb_[1] << 16),                       \
            (unsigned)hb_[2] | ((unsigned)hb_[3] << 16),                       \
            (unsigned)hb_[4] | ((unsigned)hb_[5] << 16),                       \
            (unsigned)hb_[6] | ((unsigned)hb_[7] << 16));                      \
        int row_ = (rb) * 128 + row_base;                                      \
        int sw_  = row_ * 128 + ((gr * 16) ^ ((row_ & 7) << 4));               \
        *reinterpret_cast<uint4*>(zbw + sw_) = u_;                             \
        sq_ += __shfl_xor(sq_, 1);                                             \
        sq_ += __shfl_xor(sq_, 2);                                             \
        sq_ += __shfl_xor(sq_, 4);                                             \
        if (gr == 0) sm.z2[row_] = sq_ * L2E;                                  \
    }

    {
        float4 cA, cB, nA, nB;
        ZLD(0, cA, cB)
        ZLD(1, nA, nB)
        ZCVT(0, cA, cB)  ZLD(2, cA, cB)
        ZCVT(1, nA, nB)  ZLD(3, nA, nB)
        ZCVT(2, cA, cB)
        ZCVT(3, nA, nB)
    }
#undef ZLD
#undef ZCVT

    if (tid < CROWS) sm.al[tid] = alpha[c * CROWS + tid];

    // ---- convert x (loads long in flight) + per-strip xs2 ----
    short8 b[2][2];
    float xs2v[2];
    {
        float wx[16];
#pragma unroll
        for (int h = 0; h < 2; ++h)
#pragma unroll
            for (int e = 0; e < 8; ++e)
                wx[h * 8 + e] = __expf(-0.5f * ls[h * 32 + g * 8 + e]);

        float va[16] = {xa0.x, xa0.y, xa0.z, xa0.w, xa1.x, xa1.y, xa1.z, xa1.w,
                        xa2.x, xa2.y, xa2.z, xa2.w, xa3.x, xa3.y, xa3.z, xa3.w};
        float vb[16] = {xb0.x, xb0.y, xb0.z, xb0.w, xb1.x, xb1.y, xb1.z, xb1.w,
                        xb2.x, xb2.y, xb2.z, xb2.w, xb3.x, xb3.y, xb3.z, xb3.w};
#pragma unroll
        for (int s = 0; s < 2; ++s) {
            const float* vv = (s == 0) ? va : vb;
            float sq = 0.f;
            short8 bb[2];
#pragma unroll
            for (int h = 0; h < 2; ++h)
#pragma unroll
                for (int e = 0; e < 8; ++e) {
                    ushort hh = f2bf(vv[h * 8 + e] * wx[h * 8 + e]);
                    bb[h][e] = (short)hh;
                    float xv = bf2f(hh);
                    sq = fmaf(xv, xv, sq);
                }
            b[s][0] = bb[0]; b[s][1] = bb[1];
            sq += __shfl_xor(sq, 16);
            sq += __shfl_xor(sq, 32);
            xs2v[s] = sq * L2E;
        }
    }

    __syncthreads();   // z2 complete

    // ---- per-tile skip bound: z2m[t] = min z2 over the tile's 16 rows ----
    if (tid < TILES) {
        float mn = sm.z2[tid * 16];
#pragma unroll
        for (int i = 1; i < 16; ++i) mn = fminf(mn, sm.z2[tid * 16 + i]);
        sm.z2m[tid] = mn;
    }

    __syncthreads();   // z-panel + z2 + z2m + al ready (read-only from here)

    const char* zb = reinterpret_cast<const char*>(sm.zt);
    const int rb0 = p * 128 + ((16 * g)      ^ ((p & 7) << 4));
    const int rb1 = p * 128 + ((64 + 16 * g) ^ ((p & 7) << 4));

    f32x2 accJ[2] = {{0.f, 0.f}, {0.f, 0.f}};
    const float thr_base = SKIP_THR + fminf(xs2v[0], xs2v[1]);

#pragma unroll 4
    for (int it = 0; it < TILES; ++it) {
        short8 a0 = *reinterpret_cast<const short8*>(zb + it * 2048 + rb0);
        short8 a1 = *reinterpret_cast<const short8*>(zb + it * 2048 + rb1);
        float zm = sm.z2m[it];               // wave-uniform b32 broadcast

        f32x4 t0 = {0.f, 0.f, 0.f, 0.f};
        t0 = __builtin_amdgcn_mfma_f32_16x16x32_bf16(a0, b[0][0], t0, 0, 0, 0);
        t0 = __builtin_amdgcn_mfma_f32_16x16x32_bf16(a1, b[0][1], t0, 0, 0, 0);
        f32x4 t1 = {0.f, 0.f, 0.f, 0.f};
        t1 = __builtin_amdgcn_mfma_f32_16x16x32_bf16(a0, b[1][0], t1, 0, 0, 0);
        t1 = __builtin_amdgcn_mfma_f32_16x16x32_bf16(a1, b[1][1], t1, 0, 0, 0);

        float m0 = fmaxf(fmaxf(t0[0], t0[1]), fmaxf(t0[2], t0[3]));
        float m1 = fmaxf(fmaxf(t1[0], t1[1]), fmaxf(t1[2], t1[3]));
        float bound = fmaf(fmaxf(m0, m1), L2E2, -zm);

        if (!__all(bound < thr_base)) {
            // rare path: exact per-strip contribution (R12 math)
            float4 z2 = *reinterpret_cast<const float4*>(&sm.z2[it * 16 + g * 4]);
            float4 a4 = *reinterpret_cast<const float4*>(&sm.al[it * 16 + g * 4]);
            f32x2 z2p0 = {z2.x, z2.y}, z2p1 = {z2.z, z2.w};
            f32x2 a4p0 = {a4.x, a4.y}, a4p1 = {a4.z, a4.w};
#pragma unroll
            for (int s = 0; s < 2; ++s) {
                f32x4 t = (s == 0) ? t0 : t1;
                f32x2 xsp = {xs2v[s], xs2v[s]};
                f32x2 d0 = {t[0], t[1]}, d1 = {t[2], t[3]};
                f32x2 arg0 = d0 * L2E2 - (z2p0 + xsp);
                f32x2 arg1 = d1 * L2E2 - (z2p1 + xsp);
                f32x2 pv0 = {__builtin_amdgcn_exp2f(arg0.x),
                             __builtin_amdgcn_exp2f(arg0.y)};
                f32x2 pv1 = {__builtin_amdgcn_exp2f(arg1.x),
                             __builtin_amdgcn_exp2f(arg1.y)};
                accJ[s] = accJ[s] + a4p0 * pv0;
                accJ[s] = accJ[s] + a4p1 * pv1;
            }
        }
    }

#pragma unroll
    for (int s = 0; s < 2; ++s) {
        float r = accJ[s].x + accJ[s].y;
        r += __shfl_xor(r, 16);
        r += __shfl_xor(r, 32);
        if (g == 0) atomicAdd(&out[j0 + s * 16 + p], r);
    }
}

extern "C" void kernel_launch(void* const* d_in, const int* in_sizes, int n_in,
                              void* d_out, int out_size, void* d_ws, size_t ws_size,
                              hipStream_t stream) {
    const float* x     = (const float*)d_in[0];   // (65536, 64)
    const float* z     = (const float*)d_in[1];   // (1024, 64)
    const float* alpha = (const float*)d_in[2];   // (1024,)
    const float* ls    = (const float*)d_in[3];   // (64,)
    float* out = (float*)d_out;                   // (65536, 1)

    igpr_zero<<<dim3(N_X / 1024), dim3(1024), 0, stream>>>(out);
    igpr_fused<<<dim3(N_X / 512, NCHUNK), dim3(1024), 0, stream>>>(
        x, z, alpha, ls, out);
}

// Round 19
// 20.226 us; speedup vs baseline: 1.2909x; 1.2112x over previous
//
#include <hip/hip_runtime.h>
#include <hip/hip_bf16.h>

#define N_X    65536
#define N_IND  1024
#define N_DESC 64
#define TILES  (N_IND / 16)       // 64 MFMA row-tiles (full z-panel)
#define L2E    1.4426950408889634f
#define L2E2   2.8853900817779268f
#define SKIP_THR (-60.0f)         // 2^-60 * 1024 * |alpha| ~ 4e-15 << tol

typedef __attribute__((ext_vector_type(8))) short  short8;
typedef __attribute__((ext_vector_type(4))) float  f32x4;
typedef __attribute__((ext_vector_type(2))) float  f32x2;

static __device__ __forceinline__ ushort f2bf(float f) {
    union { float f; unsigned u; } a; a.f = f;
    unsigned r = a.u + 0x7FFF + ((a.u >> 16) & 1);   // RNE to bf16
    return (ushort)(r >> 16);
}
static __device__ __forceinline__ float bf2f(ushort h) {
    union { unsigned u; float f; } a; a.u = (unsigned)h << 16;
    return a.f;
}

// ---------------------------------------------------------------------------
// Round 19 = R15 (best: 20.25 us) with the per-tile z2m ds_read_b32 replaced
// by ONE wave-scalar bound zmin = min z2 over ALL rows:
//   skip iff  L2E2*maxdot < SKIP_THR + xs2 + zmin     (mul + cmp per tile)
// Sound: z2[row] >= zmin for every row, so L2E2*maxdot - zmin - xs2 bounds
// every lane's arg. Slack vs per-tile bound ~ 700 << margin ~ 1800 -> all
// tiles still skip. Deletes 1024 b32/CU/pass, the z2m pass, and a barrier.
// zmin: 16 conflict-free b32 reads/lane (z2[lane + 64i], bank = lane%32,
// 2-way only) + 6 shfl_xor mins, once per wave after the staging barrier.
// Everything else identical to R15: pipelined 2-deep z staging, early x
// loads, in-register conversions, XOR-swizzled panel (byte colb ^=
// (row&7)<<4 both sides, rule #21), exact R12 kept path (never taken).
// C/D: col = lane&15 (x-col), row = 4*(lane>>4)+reg (z-row).
// ---------------------------------------------------------------------------
__global__ __launch_bounds__(1024) void igpr_fused(
        const float* __restrict__ x, const float* __restrict__ z,
        const float* __restrict__ alpha, const float* __restrict__ ls,
        float* __restrict__ out) {
    struct SM {
        uint4 zt[N_IND * 8];   // 1024 rows * 128 B = 128 KB (swizzled)
        float z2[N_IND];       // log2e * ||zw_i||^2
        float al[N_IND];       // alpha
    };
    __shared__ SM sm;          // 136 KB of the CU's 160 KB

    const int tid  = threadIdx.x;
    const int lane = tid & 63;
    const int wave = tid >> 6;
    const int p = lane & 15;          // x-col within strip / D col
    const int g = lane >> 4;          // k-group; D rows 4g..4g+3 (z-rows)
    const int j = blockIdx.x * 256 + wave * 16 + p;   // this lane's x column

    // ---- issue x loads immediately; consumed after z staging ----
    const float* xr = x + (size_t)j * N_DESC;
    float4 xv0 = *reinterpret_cast<const float4*>(xr + g * 8);
    float4 xv1 = *reinterpret_cast<const float4*>(xr + g * 8 + 4);
    float4 xv2 = *reinterpret_cast<const float4*>(xr + 32 + g * 8);
    float4 xv3 = *reinterpret_cast<const float4*>(xr + 32 + g * 8 + 4);
    float  alv = alpha[tid];          // N_IND == blockDim.x

    // ---- per-thread staging weights: cols gr*8 .. gr*8+7 ----
    const int gr = tid & 7;           // granule column-group (fixed per thread)
    const int row_base = tid >> 3;    // row = rb*128 + row_base
    float wz[8];
#pragma unroll
    for (int e = 0; e < 8; ++e) wz[e] = __expf(-0.5f * ls[gr * 8 + e]);

    // ---- z staging: 8 granules, 2-deep pipelined, swizzled dest ----
    char* zbw = reinterpret_cast<char*>(sm.zt);

#define ZLD(rb, A, B)                                                          \
    {                                                                          \
        const float* zp_ = z + (size_t)((rb) * 128 + row_base) * 64 + gr * 8;  \
        A = *reinterpret_cast<const float4*>(zp_);                             \
        B = *reinterpret_cast<const float4*>(zp_ + 4);                         \
    }
#define ZCVT(rb, A, B)                                                         \
    {                                                                          \
        float vv_[8] = {A.x, A.y, A.z, A.w, B.x, B.y, B.z, B.w};               \
        ushort hb_[8]; float sq_ = 0.f;                                        \
        _Pragma("unroll")                                                      \
        for (int e = 0; e < 8; ++e) {                                          \
            ushort h_ = f2bf(vv_[e] * wz[e]);                                  \
            hb_[e] = h_;                                                       \
            float vr_ = bf2f(h_);                                              \
            sq_ = fmaf(vr_, vr_, sq_);                                         \
        }                                                                      \
        uint4 u_ = make_uint4(                                                 \
            (unsigned)hb_[0] | ((unsigned)hb_[1] << 16),                       \
            (unsigned)hb_[2] | ((unsigned)hb_[3] << 16),                       \
            (unsigned)hb_[4] | ((unsigned)hb_[5] << 16),                       \
            (unsigned)hb_[6] | ((unsigned)hb_[7] << 16));                      \
        int row_ = (rb) * 128 + row_base;                                      \
        int sw_  = row_ * 128 + ((gr * 16) ^ ((row_ & 7) << 4));               \
        *reinterpret_cast<uint4*>(zbw + sw_) = u_;                             \
        sq_ += __shfl_xor(sq_, 1);                                             \
        sq_ += __shfl_xor(sq_, 2);                                             \
        sq_ += __shfl_xor(sq_, 4);                                             \
        if (gr == 0) sm.z2[row_] = sq_ * L2E;                                  \
    }

    float4 cA, cB, nA, nB;
    ZLD(0, cA, cB)
    ZLD(1, nA, nB)
    ZCVT(0, cA, cB)  ZLD(2, cA, cB)
    ZCVT(1, nA, nB)  ZLD(3, nA, nB)
    ZCVT(2, cA, cB)  ZLD(4, cA, cB)
    ZCVT(3, nA, nB)  ZLD(5, nA, nB)
    ZCVT(4, cA, cB)  ZLD(6, cA, cB)
    ZCVT(5, nA, nB)  ZLD(7, nA, nB)
    ZCVT(6, cA, cB)
    ZCVT(7, nA, nB)
#undef ZLD
#undef ZCVT

    sm.al[tid] = alv;

    // ---- convert x (loads long in flight) + xs2 ----
    short8 b0, b1;
    float xs2;
    {
        float wx[16];
#pragma unroll
        for (int h = 0; h < 2; ++h)
#pragma unroll
            for (int e = 0; e < 8; ++e)
                wx[h * 8 + e] = __expf(-0.5f * ls[h * 32 + g * 8 + e]);
        float vv[16] = {xv0.x, xv0.y, xv0.z, xv0.w, xv1.x, xv1.y, xv1.z, xv1.w,
                        xv2.x, xv2.y, xv2.z, xv2.w, xv3.x, xv3.y, xv3.z, xv3.w};
        float sq = 0.f;
        short8 bb[2];
#pragma unroll
        for (int h = 0; h < 2; ++h)
#pragma unroll
            for (int e = 0; e < 8; ++e) {
                ushort hh = f2bf(vv[h * 8 + e] * wx[h * 8 + e]);
                bb[h][e] = (short)hh;
                float xv = bf2f(hh);
                sq = fmaf(xv, xv, sq);
            }
        b0 = bb[0]; b1 = bb[1];
        sq += __shfl_xor(sq, 16);
        sq += __shfl_xor(sq, 32);
        xs2 = sq * L2E;
    }

    __syncthreads();   // z-panel + z2 + al ready (LDS read-only from here)

    // ---- wave-scalar skip bound: zmin = min z2 over all rows ----
    float zmin;
    {
        float mn = sm.z2[lane];
#pragma unroll
        for (int i = 1; i < 16; ++i) mn = fminf(mn, sm.z2[lane + 64 * i]);
        mn = fminf(mn, __shfl_xor(mn, 1));
        mn = fminf(mn, __shfl_xor(mn, 2));
        mn = fminf(mn, __shfl_xor(mn, 4));
        mn = fminf(mn, __shfl_xor(mn, 8));
        mn = fminf(mn, __shfl_xor(mn, 16));
        mn = fminf(mn, __shfl_xor(mn, 32));
        zmin = mn;
    }
    const float thr = SKIP_THR + xs2 + zmin;   // skip iff L2E2*maxdot < thr

    const char* zb = reinterpret_cast<const char*>(sm.zt);
    const int rb0 = p * 128 + ((16 * g)      ^ ((p & 7) << 4));
    const int rb1 = p * 128 + ((64 + 16 * g) ^ ((p & 7) << 4));

    f32x2 accJ = {0.f, 0.f};
    const f32x2 xs2p = {xs2, xs2};

#pragma unroll 4
    for (int it = 0; it < TILES; ++it) {
        short8 a0 = *reinterpret_cast<const short8*>(zb + it * 2048 + rb0);
        short8 a1 = *reinterpret_cast<const short8*>(zb + it * 2048 + rb1);

        f32x4 t = {0.f, 0.f, 0.f, 0.f};
        t = __builtin_amdgcn_mfma_f32_16x16x32_bf16(a0, b0, t, 0, 0, 0);
        t = __builtin_amdgcn_mfma_f32_16x16x32_bf16(a1, b1, t, 0, 0, 0);

        float maxdot = fmaxf(fmaxf(t[0], t[1]), fmaxf(t[2], t[3]));

        if (!__all(maxdot * L2E2 < thr)) {
            // rare path: a real contribution may exist in this tile
            float4 z2 = *reinterpret_cast<const float4*>(&sm.z2[it * 16 + g * 4]);
            float4 a4 = *reinterpret_cast<const float4*>(&sm.al[it * 16 + g * 4]);
            f32x2 z2p0 = {z2.x, z2.y}, z2p1 = {z2.z, z2.w};
            f32x2 d0 = {t[0], t[1]}, d1 = {t[2], t[3]};
            f32x2 arg0 = d0 * L2E2 - (z2p0 + xs2p);
            f32x2 arg1 = d1 * L2E2 - (z2p1 + xs2p);
            f32x2 pv0 = {__builtin_amdgcn_exp2f(arg0.x),
                         __builtin_amdgcn_exp2f(arg0.y)};
            f32x2 pv1 = {__builtin_amdgcn_exp2f(arg1.x),
                         __builtin_amdgcn_exp2f(arg1.y)};
            f32x2 a4p0 = {a4.x, a4.y}, a4p1 = {a4.z, a4.w};
            accJ = accJ + a4p0 * pv0;              // pk_fma
            accJ = accJ + a4p1 * pv1;              // pk_fma
        }
    }

    float r = accJ.x + accJ.y;
    r += __shfl_xor(r, 16);
    r += __shfl_xor(r, 32);
    if (g == 0) out[j] = r;
}

extern "C" void kernel_launch(void* const* d_in, const int* in_sizes, int n_in,
                              void* d_out, int out_size, void* d_ws, size_t ws_size,
                              hipStream_t stream) {
    const float* x     = (const float*)d_in[0];   // (65536, 64)
    const float* z     = (const float*)d_in[1];   // (1024, 64)
    const float* alpha = (const float*)d_in[2];   // (1024,)
    const float* ls    = (const float*)d_in[3];   // (64,)
    float* out = (float*)d_out;                   // (65536, 1)

    igpr_fused<<<dim3(N_X / 256), dim3(1024), 0, stream>>>(x, z, alpha, ls, out);
}

// Round 20
// 16.948 us; speedup vs baseline: 1.5406x; 1.1934x over previous
//
#include <hip/hip_runtime.h>
#include <hip/hip_bf16.h>

#define N_X    65536
#define N_IND  1024
#define N_DESC 64
#define TILES  (N_IND / 16)       // 64 MFMA row-tiles (full z-panel)
#define L2E    1.4426950408889634f
#define L2E2   2.8853900817779268f
#define SKIP_THR (-60.0f)         // 2^-60 * 1024 * |alpha| ~ 4e-15 << tol

typedef __attribute__((ext_vector_type(8))) short  short8;
typedef __attribute__((ext_vector_type(4))) float  f32x4;
typedef __attribute__((ext_vector_type(2))) float  f32x2;

static __device__ __forceinline__ ushort f2bf(float f) {
    union { float f; unsigned u; } a; a.f = f;
    unsigned r = a.u + 0x7FFF + ((a.u >> 16) & 1);   // RNE to bf16
    return (ushort)(r >> 16);
}
static __device__ __forceinline__ float bf2f(ushort h) {
    union { unsigned u; float f; } a; a.u = (unsigned)h << 16;
    return a.f;
}

// ---------------------------------------------------------------------------
// Round 20 = R19 + WAVE-PAIR Z-SPLIT. R19 proved the loop is purely
// ds_read_b128-issue-bound (z2m removal = 0 delta). Halve per-CU b128s
// with zero added register state / launches / atomics:
//   wave w -> column-group (w>>1), z-half (w&1): 32 tiles instead of 64.
// Per-CU loop b128: 2048 -> 1024 (each tile read by 8 waves, not 16).
// Column results combined through a tiny LDS array part[16][16] (one
// conflict-free write + barrier + one add by the even wave of each pair).
// Everything else identical to R19: pipelined 2-deep z staging, early x
// loads, in-register conversions, XOR-swizzled panel (byte colb ^=
// (row&7)<<4 both sides, rule #21), wave-scalar zmin skip bound, exact
// R12 kept path (never taken for this data).
// C/D: col = lane&15 (x-col), row = 4*(lane>>4)+reg (z-row).
// ---------------------------------------------------------------------------
__global__ __launch_bounds__(1024) void igpr_fused(
        const float* __restrict__ x, const float* __restrict__ z,
        const float* __restrict__ alpha, const float* __restrict__ ls,
        float* __restrict__ out) {
    struct SM {
        uint4 zt[N_IND * 8];   // 1024 rows * 128 B = 128 KB (swizzled)
        float z2[N_IND];       // log2e * ||zw_i||^2
        float al[N_IND];       // alpha
        float part[16][16];    // per-wave column partials (1 KB)
    };
    __shared__ SM sm;          // 137 KB of the CU's 160 KB

    const int tid  = threadIdx.x;
    const int lane = tid & 63;
    const int wave = tid >> 6;
    const int p = lane & 15;          // x-col within strip / D col
    const int g = lane >> 4;          // k-group; D rows 4g..4g+3 (z-rows)
    const int cg    = wave >> 1;      // column-group 0..7
    const int zhalf = wave & 1;       // z-half 0..1
    const int j = blockIdx.x * 256 + cg * 16 + p + (zhalf ? 128 : 0);
    // NOTE: column mapping must be IDENTICAL for both waves of a pair.
    // Pair (2c, 2c+1) shares columns; zhalf only selects the tile range.
    // j above must not depend on zhalf — fix: remove the zhalf term.
    const int jj = blockIdx.x * 256 + cg * 16 + p;   // the real column

    // ---- issue x loads immediately; consumed after z staging ----
    const float* xr = x + (size_t)jj * N_DESC;
    float4 xv0 = *reinterpret_cast<const float4*>(xr + g * 8);
    float4 xv1 = *reinterpret_cast<const float4*>(xr + g * 8 + 4);
    float4 xv2 = *reinterpret_cast<const float4*>(xr + 32 + g * 8);
    float4 xv3 = *reinterpret_cast<const float4*>(xr + 32 + g * 8 + 4);
    float  alv = alpha[tid];          // N_IND == blockDim.x

    // ---- per-thread staging weights: cols gr*8 .. gr*8+7 ----
    const int gr = tid & 7;           // granule column-group (fixed per thread)
    const int row_base = tid >> 3;    // row = rb*128 + row_base
    float wz[8];
#pragma unroll
    for (int e = 0; e < 8; ++e) wz[e] = __expf(-0.5f * ls[gr * 8 + e]);

    // ---- z staging: 8 granules, 2-deep pipelined, swizzled dest ----
    char* zbw = reinterpret_cast<char*>(sm.zt);

#define ZLD(rb, A, B)                                                          \
    {                                                                          \
        const float* zp_ = z + (size_t)((rb) * 128 + row_base) * 64 + gr * 8;  \
        A = *reinterpret_cast<const float4*>(zp_);                             \
        B = *reinterpret_cast<const float4*>(zp_ + 4);                         \
    }
#define ZCVT(rb, A, B)                                                         \
    {                                                                          \
        float vv_[8] = {A.x, A.y, A.z, A.w, B.x, B.y, B.z, B.w};               \
        ushort hb_[8]; float sq_ = 0.f;                                        \
        _Pragma("unroll")                                                      \
        for (int e = 0; e < 8; ++e) {                                          \
            ushort h_ = f2bf(vv_[e] * wz[e]);                                  \
            hb_[e] = h_;                                                       \
            float vr_ = bf2f(h_);                                              \
            sq_ = fmaf(vr_, vr_, sq_);                                         \
        }                                                                      \
        uint4 u_ = make_uint4(                                                 \
            (unsigned)hb_[0] | ((unsigned)hb_[1] << 16),                       \
            (unsigned)hb_[2] | ((unsigned)hb_[3] << 16),                       \
            (unsigned)hb_[4] | ((unsigned)hb_[5] << 16),                       \
            (unsigned)hb_[6] | ((unsigned)hb_[7] << 16));                      \
        int row_ = (rb) * 128 + row_base;                                      \
        int sw_  = row_ * 128 + ((gr * 16) ^ ((row_ & 7) << 4));               \
        *reinterpret_cast<uint4*>(zbw + sw_) = u_;                             \
        sq_ += __shfl_xor(sq_, 1);                                             \
        sq_ += __shfl_xor(sq_, 2);                                             \
        sq_ += __shfl_xor(sq_, 4);                                             \
        if (gr == 0) sm.z2[row_] = sq_ * L2E;                                  \
    }

    float4 cA, cB, nA, nB;
    ZLD(0, cA, cB)
    ZLD(1, nA, nB)
    ZCVT(0, cA, cB)  ZLD(2, cA, cB)
    ZCVT(1, nA, nB)  ZLD(3, nA, nB)
    ZCVT(2, cA, cB)  ZLD(4, cA, cB)
    ZCVT(3, nA, nB)  ZLD(5, nA, nB)
    ZCVT(4, cA, cB)  ZLD(6, cA, cB)
    ZCVT(5, nA, nB)  ZLD(7, nA, nB)
    ZCVT(6, cA, cB)
    ZCVT(7, nA, nB)
#undef ZLD
#undef ZCVT

    sm.al[tid] = alv;

    // ---- convert x (loads long in flight) + xs2 ----
    short8 b0, b1;
    float xs2;
    {
        float wx[16];
#pragma unroll
        for (int h = 0; h < 2; ++h)
#pragma unroll
            for (int e = 0; e < 8; ++e)
                wx[h * 8 + e] = __expf(-0.5f * ls[h * 32 + g * 8 + e]);
        float vv[16] = {xv0.x, xv0.y, xv0.z, xv0.w, xv1.x, xv1.y, xv1.z, xv1.w,
                        xv2.x, xv2.y, xv2.z, xv2.w, xv3.x, xv3.y, xv3.z, xv3.w};
        float sq = 0.f;
        short8 bb[2];
#pragma unroll
        for (int h = 0; h < 2; ++h)
#pragma unroll
            for (int e = 0; e < 8; ++e) {
                ushort hh = f2bf(vv[h * 8 + e] * wx[h * 8 + e]);
                bb[h][e] = (short)hh;
                float xv = bf2f(hh);
                sq = fmaf(xv, xv, sq);
            }
        b0 = bb[0]; b1 = bb[1];
        sq += __shfl_xor(sq, 16);
        sq += __shfl_xor(sq, 32);
        xs2 = sq * L2E;
    }

    __syncthreads();   // z-panel + z2 + al ready (LDS read-only from here)

    // ---- wave-scalar skip bound: zmin = min z2 over all rows ----
    float zmin;
    {
        float mn = sm.z2[lane];
#pragma unroll
        for (int i = 1; i < 16; ++i) mn = fminf(mn, sm.z2[lane + 64 * i]);
        mn = fminf(mn, __shfl_xor(mn, 1));
        mn = fminf(mn, __shfl_xor(mn, 2));
        mn = fminf(mn, __shfl_xor(mn, 4));
        mn = fminf(mn, __shfl_xor(mn, 8));
        mn = fminf(mn, __shfl_xor(mn, 16));
        mn = fminf(mn, __shfl_xor(mn, 32));
        zmin = mn;
    }
    const float thr = SKIP_THR + xs2 + zmin;   // skip iff L2E2*maxdot < thr

    const char* zb = reinterpret_cast<const char*>(sm.zt);
    const int rb0 = p * 128 + ((16 * g)      ^ ((p & 7) << 4));
    const int rb1 = p * 128 + ((64 + 16 * g) ^ ((p & 7) << 4));

    f32x2 accJ = {0.f, 0.f};
    const f32x2 xs2p = {xs2, xs2};
    const int it0 = zhalf * (TILES / 2);

#pragma unroll 4
    for (int ii = 0; ii < TILES / 2; ++ii) {
        const int it = it0 + ii;
        short8 a0 = *reinterpret_cast<const short8*>(zb + it * 2048 + rb0);
        short8 a1 = *reinterpret_cast<const short8*>(zb + it * 2048 + rb1);

        f32x4 t = {0.f, 0.f, 0.f, 0.f};
        t = __builtin_amdgcn_mfma_f32_16x16x32_bf16(a0, b0, t, 0, 0, 0);
        t = __builtin_amdgcn_mfma_f32_16x16x32_bf16(a1, b1, t, 0, 0, 0);

        float maxdot = fmaxf(fmaxf(t[0], t[1]), fmaxf(t[2], t[3]));

        if (!__all(maxdot * L2E2 < thr)) {
            // rare path: a real contribution may exist in this tile
            float4 z2 = *reinterpret_cast<const float4*>(&sm.z2[it * 16 + g * 4]);
            float4 a4 = *reinterpret_cast<const float4*>(&sm.al[it * 16 + g * 4]);
            f32x2 z2p0 = {z2.x, z2.y}, z2p1 = {z2.z, z2.w};
            f32x2 d0 = {t[0], t[1]}, d1 = {t[2], t[3]};
            f32x2 arg0 = d0 * L2E2 - (z2p0 + xs2p);
            f32x2 arg1 = d1 * L2E2 - (z2p1 + xs2p);
            f32x2 pv0 = {__builtin_amdgcn_exp2f(arg0.x),
                         __builtin_amdgcn_exp2f(arg0.y)};
            f32x2 pv1 = {__builtin_amdgcn_exp2f(arg1.x),
                         __builtin_amdgcn_exp2f(arg1.y)};
            f32x2 a4p0 = {a4.x, a4.y}, a4p1 = {a4.z, a4.w};
            accJ = accJ + a4p0 * pv0;              // pk_fma
            accJ = accJ + a4p1 * pv1;              // pk_fma
        }
    }

    float r = accJ.x + accJ.y;
    r += __shfl_xor(r, 16);
    r += __shfl_xor(r, 32);
    if (g == 0) sm.part[wave][p] = r;

    __syncthreads();   // both halves' partials visible

    if (zhalf == 0 && g == 0)
        out[jj] = sm.part[wave][p] + sm.part[wave + 1][p];
}

extern "C" void kernel_launch(void* const* d_in, const int* in_sizes, int n_in,
                              void* d_out, int out_size, void* d_ws, size_t ws_size,
                              hipStream_t stream) {
    const float* x     = (const float*)d_in[0];   // (65536, 64)
    const float* z     = (const float*)d_in[1];   // (1024, 64)
    const float* alpha = (const float*)d_in[2];   // (1024,)
    const float* ls    = (const float*)d_in[3];   // (64,)
    float* out = (float*)d_out;                   // (65536, 1)

    igpr_fused<<<dim3(N_X / 256), dim3(1024), 0, stream>>>(x, z, alpha, ls, out);
}